// Round 18
// baseline (226.485 us; speedup 1.0000x reference)
//
#include <hip/hip_runtime.h>
#include <hip/hip_bf16.h>
#include <stdint.h>

typedef __attribute__((ext_vector_type(4))) float f32x4;
typedef __attribute__((ext_vector_type(8))) short short8;
typedef __attribute__((ext_vector_type(4))) unsigned short u16x4;
typedef unsigned short us;

#define DEV __device__ __forceinline__
#define MFMA16(a, b, c) __builtin_amdgcn_mfma_f32_16x16x32_bf16(a, b, c, 0, 0, 0)

DEV us f2b(float x) {
  union { float f; uint32_t u; } c; c.f = x;
  uint32_t r = (c.u + 0x7fffu + ((c.u >> 16) & 1u)) >> 16;
  return (us)r;
}
DEV float b2f(us x) {
  union { uint32_t u; float f; } c; c.u = ((uint32_t)x) << 16;
  return c.f;
}

DEV void gload_lds16(const void* g, void* l) {
  __builtin_amdgcn_global_load_lds((const __attribute__((address_space(1))) void*)g,
                                   (__attribute__((address_space(3))) void*)l, 16, 0, 0);
}

// ---------------- kernel 1: fp32 -> bf16 conversions ----------------
__global__ __launch_bounds__(256) void prep_k(
    const float* __restrict__ x, const float* __restrict__ wproj,
    const float* __restrict__ wg, const float* __restrict__ wo,
    us* __restrict__ Xbf, us* __restrict__ Wbf, us* __restrict__ Wobf) {
  int i = blockIdx.x * 256 + threadIdx.x;
  const float* src; us* dst;
  if (i < 524288)               { src = x     + (size_t)i * 4;                  dst = Xbf + (size_t)i * 4; }
  else if (i < 524288 + 786432) { int j = i - 524288;            src = wproj + (size_t)j * 4; dst = Wbf + (size_t)j * 4; }
  else if (i < 524288 + 786432 + 262144) { int j = i - (524288 + 786432); src = wg + (size_t)j * 4; dst = Wbf + 3145728 + (size_t)j * 4; }
  else                          { int j = i - (524288 + 786432 + 262144); src = wo + (size_t)j * 4; dst = Wobf + (size_t)j * 4; }
  f32x4 v = *(const f32x4*)src;
  u16x4 o; o.x = f2b(v.x); o.y = f2b(v.y); o.z = f2b(v.z); o.w = f2b(v.w);
  *(u16x4*)dst = o;
}

// ---------------- shared GEMM core (m97-style, 128x128) ----------------
DEV void gemm_stage(char* sm, const us* A, const us* Bw,
                    int tileMrow, int tileNrow, int buf, int kt, int lane, int wid) {
  const char* gA = (const char*)A;
  const char* gB = (const char*)Bw;
#pragma unroll
  for (int i = 0; i < 2; ++i) {
    int c = wid * 2 + i;
    int off = c * 1024 + lane * 16;
    int r = off >> 6, cb = off & 63;
    gload_lds16(gA + ((size_t)(tileMrow + r) * 2048) + kt * 64 + cb, sm + buf * 8192 + c * 1024);
    gload_lds16(gB + ((size_t)(tileNrow + r) * 2048) + kt * 64 + cb, sm + 16384 + buf * 8192 + c * 1024);
  }
}

DEV void gemm_main(const us* A, const us* Bw,
                   int tileMrow, int tileNrow, f32x4 acc[4][4], char* sm) {
  int tid = threadIdx.x, lane = tid & 63, wid = tid >> 6;
  int wr = wid >> 1, wc = wid & 1;
  gemm_stage(sm, A, Bw, tileMrow, tileNrow, 0, 0, lane, wid);
  for (int kt = 0; kt < 32; ++kt) {
    __syncthreads();
    if (kt < 31) gemm_stage(sm, A, Bw, tileMrow, tileNrow, (kt + 1) & 1, kt + 1, lane, wid);
    int ab = (kt & 1) * 8192;
    int rb = (lane & 15) * 64 + ((lane >> 4) * 16);
    short8 af[4], bf[4];
#pragma unroll
    for (int mi = 0; mi < 4; ++mi)
      af[mi] = *(const short8*)(sm + ab + (wr * 64 + mi * 16) * 64 + rb);
#pragma unroll
    for (int ni = 0; ni < 4; ++ni)
      bf[ni] = *(const short8*)(sm + 16384 + ab + (wc * 64 + ni * 16) * 64 + rb);
#pragma unroll
    for (int mi = 0; mi < 4; ++mi)
#pragma unroll
      for (int ni = 0; ni < 4; ++ni)
        acc[mi][ni] = MFMA16(af[mi], bf[ni], acc[mi][ni]);
  }
}

// ---------------- kernel 2: QKV+gate projection ----------------
__global__ __launch_bounds__(256) void gemm_qkvg_k(
    const us* __restrict__ Xbf, const us* __restrict__ Wbf,
    us* __restrict__ Qb, us* __restrict__ Kb, us* __restrict__ Vt,
    float* __restrict__ G, const float* __restrict__ bg) {
  __shared__ char sm[32768];
  int bid = blockIdx.x;
  int swz = (bid & 7) * 64 + (bid >> 3);
  int tileM = swz >> 5, tileN = swz & 31;
  f32x4 acc[4][4] = {};
  gemm_main(Xbf, Wbf, tileM * 128, tileN * 128, acc, sm);
  int lane = threadIdx.x & 63, wid = threadIdx.x >> 6;
  int wr = wid >> 1, wc = wid & 1;
#pragma unroll
  for (int mi = 0; mi < 4; ++mi)
#pragma unroll
    for (int ni = 0; ni < 4; ++ni)
#pragma unroll
      for (int j = 0; j < 4; ++j) {
        int row = tileM * 128 + wr * 64 + mi * 16 + ((lane >> 4) << 2) + j;
        int col = tileN * 128 + wc * 64 + ni * 16 + (lane & 15);
        float v = acc[mi][ni][j];
        int b = row >> 10, l = row & 1023;
        if (col < 3072) {
          int h = col / 192, r = col - h * 192;
          size_t base = ((size_t)(b * 16 + h) * 1024 + l) * 64;
          if (r < 64)        Qb[base + r] = f2b(v * 0.125f);
          else if (r < 128)  Kb[base + (r - 64)] = f2b(v);
          else               Vt[((size_t)(b * 16 + h) * 64 + (r - 128)) * 1024 + l] = f2b(v);
        } else {
          int e = col - 3072;
          float s = v + bg[e];
          G[(size_t)row * 1024 + e] = 1.f / (1.f + __expf(-s));
        }
      }
}

// ---------------- kernel 3: fused QK^T + bias + exp -> E, lsum partials ----------------
// (R15 structure: global_load_lds bias staging, 32-lk dbuf tiles, 8 waves x 2 heads)
__global__ __launch_bounds__(512) void qke_k(
    const us* __restrict__ Qb, const us* __restrict__ Kb,
    const float* __restrict__ bias, us* __restrict__ E,
    float* __restrict__ lpart) {
  __shared__ float bt[2][16][516];   // [buf][q][lk*16+h], row 2064B
  int tid = threadIdx.x, lane = tid & 63, w = tid >> 6;
  int la = lane & 15, lg = lane >> 4;
  int bid = blockIdx.x;
  int b = (bid & 7) >> 2, kc = bid & 3;  // xcd = bid%8 = b*4+kc for all qt
  int qt = bid >> 3;
  int lq0 = qt * 16, lk00 = kc * 256;

  short8 qf[2][2];
#pragma unroll
  for (int s = 0; s < 2; ++s) {
    size_t bh = (size_t)(b * 16 + w * 2 + s);
#pragma unroll
    for (int ks = 0; ks < 2; ++ks)
      qf[s][ks] = *(const short8*)(Qb + bh * 65536 + (size_t)(lq0 + la) * 64 + ks * 32 + lg * 8);
  }
  const char* bsrc = (const char*)(bias + ((size_t)b << 24) + ((size_t)lq0 << 14));

#pragma unroll
  for (int i = 0; i < 4; ++i) {
    int q = w * 2 + (i >> 1), half = i & 1;
    gload_lds16(bsrc + ((size_t)q << 16) + ((size_t)(lk00 + half * 16) << 6) + lane * 16,
                (char*)&bt[0][q][half * 256] + lane * 16);
  }

  float lacc[2] = {0.f, 0.f};
#pragma unroll 1
  for (int t = 0; t < 8; ++t) {
    __syncthreads();
    if (t < 7) {
      int lkt = lk00 + (t + 1) * 32;
      int nb = (t + 1) & 1;
#pragma unroll
      for (int i = 0; i < 4; ++i) {
        int q = w * 2 + (i >> 1), half = i & 1;
        gload_lds16(bsrc + ((size_t)q << 16) + ((size_t)(lkt + half * 16) << 6) + lane * 16,
                    (char*)&bt[nb][q][half * 256] + lane * 16);
      }
    }
    int cb = t & 1;
    int lkg = lk00 + t * 32;
#pragma unroll
    for (int s = 0; s < 2; ++s) {
      int h = w * 2 + s;
      const us* Kh = Kb + (size_t)(b * 16 + h) * 65536;
#pragma unroll
      for (int fr = 0; fr < 2; ++fr) {
        const us* kr = Kh + (size_t)(lkg + fr * 16 + la) * 64 + lg * 8;
        short8 kf0 = *(const short8*)kr;
        short8 kf1 = *(const short8*)(kr + 32);
        f32x4 a;
#pragma unroll
        for (int j = 0; j < 4; ++j)
          a[j] = bt[cb][la][(fr * 16 + lg * 4 + j) * 16 + h];
        a = MFMA16(kf0, qf[s][0], a);
        a = MFMA16(kf1, qf[s][1], a);
        u16x4 ev;
#pragma unroll
        for (int j = 0; j < 4; ++j) {
          float e = __expf(a[j]);
          lacc[s] += e;
          ev[j] = f2b(e);
        }
        *(u16x4*)(E + (((size_t)(b * 1024 + lq0 + la) * 16 + h) << 10) + lkg + fr * 16 + lg * 4) = ev;
      }
    }
  }
#pragma unroll
  for (int s = 0; s < 2; ++s) {
    float v = lacc[s];
    v += __shfl_xor(v, 16);
    v += __shfl_xor(v, 32);
    if (lg == 0) lpart[kc * 32768 + (b * 16 + w * 2 + s) * 1024 + lq0 + la] = v;
  }
}

// ---------------- kernel 4: PV + transposed probs + gate ----------------
// Block (b,h,32q), 4 waves x 256 lk. SINGLE CHANGE vs R16: LDS 49.8KB -> 16.8KB
// (reduce buffer reuses pb region, done in two 16-row halves) -> 8 blocks/CU.
__global__ __launch_bounds__(256) void pv_k(
    const us* __restrict__ E, const us* __restrict__ Vt,
    const float* __restrict__ lpart, const float* __restrict__ G,
    float* __restrict__ outa, us* __restrict__ Ybf) {
  __shared__ char sm[16768];           // pb: 4x4096 = 16384 | lv: 128B @16640
  float* lv = (float*)(sm + 16640);
  int tid = threadIdx.x, lane = tid & 63, w = tid >> 6;
  int la = lane & 15, lg = lane >> 4;
  int bid = blockIdx.x;
  int g = bid >> 8, qt = (bid >> 3) & 31, xx = bid & 7;
  int bh = g * 8 + xx;
  int b = bh >> 4, h = bh & 15;
  int qb = qt * 32;
  if (tid < 32) {
    int r = bh * 1024 + qb + tid;
    float s = lpart[r] + lpart[32768 + r] + lpart[65536 + r] + lpart[98304 + r];
    lv[tid] = 1.f / s;
  }
  __syncthreads();
  char* pb = sm + w * 4096;  // [32 q][64 lk] bf16, chunk-XOR swizzle
  const us* Vh = Vt + (size_t)bh * 65536;
  f32x4 yacc[2][4] = {};
  int lkw = w * 256;

#pragma unroll 1
  for (int cc = 0; cc < 4; ++cc) {
    int lk0 = lkw + cc * 64;
    // stage E tile (reg-staged so dest can be swizzled)
#pragma unroll
    for (int it = 0; it < 4; ++it) {
      int ci = it * 64 + lane;
      int q = ci >> 3, c16 = ci & 7;
      short8 ev = *(const short8*)(E + (((size_t)(b * 1024 + qb + q) * 16 + h) << 10) + lk0 + c16 * 8);
      *(short8*)(pb + q * 128 + ((c16 * 16) ^ ((q & 7) << 4))) = ev;
    }
    // transposed probs: outa[b][lk][h][qb..qb+32)
#pragma unroll
    for (int it = 0; it < 8; ++it) {
      int idx = it * 64 + lane;
      int lkL = idx >> 3, q4 = idx & 7;
      f32x4 ov;
#pragma unroll
      for (int i = 0; i < 4; ++i) {
        int q = q4 * 4 + i;
        us e = *(const us*)(pb + q * 128 + ((2 * lkL) ^ ((q & 7) << 4)));
        ov[i] = b2f(e) * lv[q];
      }
      *(f32x4*)(outa + (((size_t)(b * 1024 + lk0 + lkL) * 16 + h) << 10) + qb + q4 * 4) = ov;
    }
    // PV
#pragma unroll
    for (int ks = 0; ks < 2; ++ks) {
      short8 pa[2];
#pragma unroll
      for (int qh = 0; qh < 2; ++qh) {
        int row = qh * 16 + la;
        pa[qh] = *(const short8*)(pb + row * 128 + ((ks * 64 + lg * 16) ^ ((row & 7) << 4)));
      }
#pragma unroll
      for (int ni = 0; ni < 4; ++ni) {
        short8 vf = *(const short8*)(Vh + (size_t)(ni * 16 + la) * 1024 + lk0 + ks * 32 + lg * 8);
        yacc[0][ni] = MFMA16(pa[0], vf, yacc[0][ni]);
        yacc[1][ni] = MFMA16(pa[1], vf, yacc[1][ni]);
      }
    }
  }

  // cross-wave O reduce + linv + gate, in two 16-row halves reusing pb region
#pragma unroll 1
  for (int half = 0; half < 2; ++half) {
    __syncthreads();  // pb/red reads of previous phase done
    float* red = (float*)(sm + w * 4160);  // 16 rows x 65 floats per wave
#pragma unroll
    for (int ni = 0; ni < 4; ++ni)
#pragma unroll
      for (int j = 0; j < 4; ++j)
        red[(lg * 4 + j) * 65 + ni * 16 + la] = yacc[half][ni][j];
    __syncthreads();
#pragma unroll
    for (int rr = 0; rr < 4; ++rr) {
      int e = rr * 256 + tid;
      int r = e >> 6, c = e & 63;
      float s = *(const float*)(sm + 0 * 4160 + (r * 65 + c) * 4) +
                *(const float*)(sm + 1 * 4160 + (r * 65 + c) * 4) +
                *(const float*)(sm + 2 * 4160 + (r * 65 + c) * 4) +
                *(const float*)(sm + 3 * 4160 + (r * 65 + c) * 4);
      int row = half * 16 + r;
      size_t gi = (((size_t)(b * 1024 + qb + row)) << 10) + h * 64 + c;
      Ybf[gi] = f2b(s * lv[row] * G[gi]);
    }
  }
}

// ---------------- kernel 5: output projection ----------------
__global__ __launch_bounds__(256) void gemm_out_k(
    const us* __restrict__ Ybf, const us* __restrict__ Wobf,
    const float* __restrict__ bo, float* __restrict__ outy) {
  __shared__ char sm[32768];
  int bid = blockIdx.x;
  int swz = (bid & 7) * 16 + (bid >> 3);
  int tileM = swz >> 3, tileN = swz & 7;
  f32x4 acc[4][4] = {};
  gemm_main(Ybf, Wobf, tileM * 128, tileN * 128, acc, sm);
  int lane = threadIdx.x & 63, wid = threadIdx.x >> 6;
  int wr = wid >> 1, wc = wid & 1;
#pragma unroll
  for (int mi = 0; mi < 4; ++mi)
#pragma unroll
    for (int ni = 0; ni < 4; ++ni)
#pragma unroll
      for (int j = 0; j < 4; ++j) {
        int row = tileM * 128 + wr * 64 + mi * 16 + ((lane >> 4) << 2) + j;
        int col = tileN * 128 + wc * 64 + ni * 16 + (lane & 15);
        outy[(size_t)row * 1024 + col] = acc[mi][ni][j] + bo[col];
      }
}

extern "C" void kernel_launch(void* const* d_in, const int* in_sizes, int n_in,
                              void* d_out, int out_size, void* d_ws, size_t ws_size,
                              hipStream_t stream) {
  const float* x     = (const float*)d_in[0];
  const float* bias  = (const float*)d_in[1];
  const float* wproj = (const float*)d_in[2];
  const float* wo    = (const float*)d_in[3];
  const float* bo    = (const float*)d_in[4];
  const float* wg    = (const float*)d_in[5];
  const float* bg    = (const float*)d_in[6];
  float* outy = (float*)d_out;
  float* outa = outy + 2097152;  // y (2M f32), then probs (B,Lk,H,Lq) f32

  char* ws = (char*)d_ws;
  us*    Xbf  = (us*)(ws);
  us*    Wbf  = (us*)(ws + 4  * 1024 * 1024);
  us*    Wobf = (us*)(ws + 12 * 1024 * 1024);
  us*    Qb   = (us*)(ws + 14 * 1024 * 1024);
  us*    Kb   = (us*)(ws + 18 * 1024 * 1024);
  us*    Vt   = (us*)(ws + 22 * 1024 * 1024);
  float* G    = (float*)(ws + 26 * 1024 * 1024);
  us*    Ybf  = (us*)(ws + 34 * 1024 * 1024);
  float* lpart= (float*)(ws + (size_t)38 * 1024 * 1024);   // 512 KB
  us*    E    = (us*)   (ws + (size_t)40 * 1024 * 1024);   // 64 MB bf16
  if (ws_size < (size_t)104 * 1024 * 1024) return;

  prep_k<<<dim3(7168), dim3(256), 0, stream>>>(x, wproj, wg, wo, Xbf, Wbf, Wobf);
  gemm_qkvg_k<<<dim3(512), dim3(256), 0, stream>>>(Xbf, Wbf, Qb, Kb, Vt, G, bg);
  qke_k<<<dim3(512), dim3(512), 0, stream>>>(Qb, Kb, bias, E, lpart);
  pv_k<<<dim3(1024), dim3(256), 0, stream>>>(E, Vt, lpart, G, outa, Ybf);
  gemm_out_k<<<dim3(128), dim3(256), 0, stream>>>(Ybf, Wobf, bo, outy);
}

// Round 19
// 199.967 us; speedup vs baseline: 1.1326x; 1.1326x over previous
//
#include <hip/hip_runtime.h>
#include <hip/hip_bf16.h>
#include <stdint.h>

typedef __attribute__((ext_vector_type(4))) float f32x4;
typedef __attribute__((ext_vector_type(8))) short short8;
typedef __attribute__((ext_vector_type(4))) unsigned short u16x4;
typedef unsigned short us;

#define DEV __device__ __forceinline__
#define MFMA16(a, b, c) __builtin_amdgcn_mfma_f32_16x16x32_bf16(a, b, c, 0, 0, 0)

DEV us f2b(float x) {
  union { float f; uint32_t u; } c; c.f = x;
  uint32_t r = (c.u + 0x7fffu + ((c.u >> 16) & 1u)) >> 16;
  return (us)r;
}
DEV float b2f(us x) {
  union { uint32_t u; float f; } c; c.u = ((uint32_t)x) << 16;
  return c.f;
}

DEV void gload_lds16(const void* g, void* l) {
  __builtin_amdgcn_global_load_lds((const __attribute__((address_space(1))) void*)g,
                                   (__attribute__((address_space(3))) void*)l, 16, 0, 0);
}

// ---------------- kernel 1: fp32 -> bf16 conversions ----------------
__global__ __launch_bounds__(256) void prep_k(
    const float* __restrict__ x, const float* __restrict__ wproj,
    const float* __restrict__ wg, const float* __restrict__ wo,
    us* __restrict__ Xbf, us* __restrict__ Wbf, us* __restrict__ Wobf) {
  int i = blockIdx.x * 256 + threadIdx.x;
  const float* src; us* dst;
  if (i < 524288)               { src = x     + (size_t)i * 4;                  dst = Xbf + (size_t)i * 4; }
  else if (i < 524288 + 786432) { int j = i - 524288;            src = wproj + (size_t)j * 4; dst = Wbf + (size_t)j * 4; }
  else if (i < 524288 + 786432 + 262144) { int j = i - (524288 + 786432); src = wg + (size_t)j * 4; dst = Wbf + 3145728 + (size_t)j * 4; }
  else                          { int j = i - (524288 + 786432 + 262144); src = wo + (size_t)j * 4; dst = Wobf + (size_t)j * 4; }
  f32x4 v = *(const f32x4*)src;
  u16x4 o; o.x = f2b(v.x); o.y = f2b(v.y); o.z = f2b(v.z); o.w = f2b(v.w);
  *(u16x4*)dst = o;
}

// ---------------- shared GEMM core (m97-style, 128x128) ----------------
DEV void gemm_stage(char* sm, const us* A, const us* Bw,
                    int tileMrow, int tileNrow, int buf, int kt, int lane, int wid) {
  const char* gA = (const char*)A;
  const char* gB = (const char*)Bw;
#pragma unroll
  for (int i = 0; i < 2; ++i) {
    int c = wid * 2 + i;
    int off = c * 1024 + lane * 16;
    int r = off >> 6, cb = off & 63;
    gload_lds16(gA + ((size_t)(tileMrow + r) * 2048) + kt * 64 + cb, sm + buf * 8192 + c * 1024);
    gload_lds16(gB + ((size_t)(tileNrow + r) * 2048) + kt * 64 + cb, sm + 16384 + buf * 8192 + c * 1024);
  }
}

DEV void gemm_main(const us* A, const us* Bw,
                   int tileMrow, int tileNrow, f32x4 acc[4][4], char* sm) {
  int tid = threadIdx.x, lane = tid & 63, wid = tid >> 6;
  int wr = wid >> 1, wc = wid & 1;
  gemm_stage(sm, A, Bw, tileMrow, tileNrow, 0, 0, lane, wid);
  for (int kt = 0; kt < 32; ++kt) {
    __syncthreads();
    if (kt < 31) gemm_stage(sm, A, Bw, tileMrow, tileNrow, (kt + 1) & 1, kt + 1, lane, wid);
    int ab = (kt & 1) * 8192;
    int rb = (lane & 15) * 64 + ((lane >> 4) * 16);
    short8 af[4], bf[4];
#pragma unroll
    for (int mi = 0; mi < 4; ++mi)
      af[mi] = *(const short8*)(sm + ab + (wr * 64 + mi * 16) * 64 + rb);
#pragma unroll
    for (int ni = 0; ni < 4; ++ni)
      bf[ni] = *(const short8*)(sm + 16384 + ab + (wc * 64 + ni * 16) * 64 + rb);
#pragma unroll
    for (int mi = 0; mi < 4; ++mi)
#pragma unroll
      for (int ni = 0; ni < 4; ++ni)
        acc[mi][ni] = MFMA16(af[mi], bf[ni], acc[mi][ni]);
  }
}

// ---------------- kernel 2: QKV+gate projection ----------------
__global__ __launch_bounds__(256) void gemm_qkvg_k(
    const us* __restrict__ Xbf, const us* __restrict__ Wbf,
    us* __restrict__ Qb, us* __restrict__ Kb, us* __restrict__ Vt,
    float* __restrict__ G, const float* __restrict__ bg) {
  __shared__ char sm[32768];
  int bid = blockIdx.x;
  int swz = (bid & 7) * 64 + (bid >> 3);
  int tileM = swz >> 5, tileN = swz & 31;
  f32x4 acc[4][4] = {};
  gemm_main(Xbf, Wbf, tileM * 128, tileN * 128, acc, sm);
  int lane = threadIdx.x & 63, wid = threadIdx.x >> 6;
  int wr = wid >> 1, wc = wid & 1;
#pragma unroll
  for (int mi = 0; mi < 4; ++mi)
#pragma unroll
    for (int ni = 0; ni < 4; ++ni)
#pragma unroll
      for (int j = 0; j < 4; ++j) {
        int row = tileM * 128 + wr * 64 + mi * 16 + ((lane >> 4) << 2) + j;
        int col = tileN * 128 + wc * 64 + ni * 16 + (lane & 15);
        float v = acc[mi][ni][j];
        int b = row >> 10, l = row & 1023;
        if (col < 3072) {
          int h = col / 192, r = col - h * 192;
          size_t base = ((size_t)(b * 16 + h) * 1024 + l) * 64;
          if (r < 64)        Qb[base + r] = f2b(v * 0.125f);
          else if (r < 128)  Kb[base + (r - 64)] = f2b(v);
          else               Vt[((size_t)(b * 16 + h) * 64 + (r - 128)) * 1024 + l] = f2b(v);
        } else {
          int e = col - 3072;
          float s = v + bg[e];
          G[(size_t)row * 1024 + e] = 1.f / (1.f + __expf(-s));
        }
      }
}

// ---------------- kernel 3: fused QK^T + bias + exp -> E, lsum partials ----------------
// R11-best: block (b, qt:16q, kc:256lk, hg:8 heads); 8 waves, one head/wave.
// Bias staged in 128-lk halves (8-deep load queue), double-buffered, TWO
// barriers per block; half-1 loads issued before half-0 compute.
__global__ __launch_bounds__(512, 4) void qke_k(
    const us* __restrict__ Qb, const us* __restrict__ Kb,
    const float* __restrict__ bias, us* __restrict__ E,
    float* __restrict__ lpart) {
  __shared__ float bt[2][4][8][16][36];   // [buf][chunk32][hl][q][slk^ pad36]
  int tid = threadIdx.x, lane = tid & 63, w = tid >> 6;
  int la = lane & 15, lg = lane >> 4;
  int bid = blockIdx.x;
  int b = (bid & 7) >> 2, kc = bid & 3;
  int hg = (bid >> 3) & 1, qt = bid >> 4;
  int lq0 = qt * 16, lk00 = kc * 256;
  int h = hg * 8 + w, hh = w;

  short8 qf[2];
  {
    size_t bh = (size_t)(b * 16 + h);
#pragma unroll
    for (int ks = 0; ks < 2; ++ks)
      qf[ks] = *(const short8*)(Qb + bh * 65536 + (size_t)(lq0 + la) * 64 + ks * 32 + lg * 8);
  }
  const us* Kh = Kb + (size_t)(b * 16 + h) * 65536;
  const float* bsrc = bias + ((size_t)b << 24) + ((size_t)lq0 << 14) + hg * 8;
  us* Erow = E + (((size_t)(b * 1024 + lq0 + la) * 16 + h) << 10);

  f32x4 vv[8];
  // ---- stage half 0: 8 loads issued back-to-back, then writes ----
#pragma unroll
  for (int i = 0; i < 8; ++i) {
    int f = i * 512 + tid;
    int h4 = f & 1, lk = (f >> 1) & 127, q = f >> 8;
    vv[i] = *(const f32x4*)(bsrc + ((size_t)q << 14) + ((size_t)(lk00 + lk) << 4) + h4 * 4);
  }
#pragma unroll
  for (int i = 0; i < 8; ++i) {
    int f = i * 512 + tid;
    int h4 = f & 1, lk = (f >> 1) & 127, q = f >> 8;
    int c = lk >> 5, slk = lk & 31;
#pragma unroll
    for (int e = 0; e < 4; ++e) {
      int hl = h4 * 4 + e;
      bt[0][c][hl][q][slk ^ (hl << 2)] = vv[i][e];
    }
  }
  __syncthreads();   // barrier 1: half-0 tile ready

  float lacc = 0.f;
  // ---- issue half-1 loads (latency hides under half-0 compute) ----
#pragma unroll
  for (int i = 0; i < 8; ++i) {
    int f = i * 512 + tid;
    int h4 = f & 1, lk = (f >> 1) & 127, q = f >> 8;
    vv[i] = *(const f32x4*)(bsrc + ((size_t)q << 14) + ((size_t)(lk00 + 128 + lk) << 4) + h4 * 4);
  }
  // ---- compute half 0: 8 fr, no barriers ----
#pragma unroll
  for (int fr = 0; fr < 8; ++fr) {
    int c = fr >> 1;
    const us* kr = Kh + (size_t)(lk00 + fr * 16 + la) * 64 + lg * 8;
    short8 kf0 = *(const short8*)kr;
    short8 kf1 = *(const short8*)(kr + 32);
    int lkb = ((fr & 1) * 16 + lg * 4) ^ (hh << 2);
    f32x4 a = *(const f32x4*)&bt[0][c][hh][la][lkb];
    a = MFMA16(kf0, qf[0], a);
    a = MFMA16(kf1, qf[1], a);
    u16x4 ev;
#pragma unroll
    for (int j = 0; j < 4; ++j) {
      float e = __expf(a[j]);
      lacc += e;
      ev[j] = f2b(e);
    }
    *(u16x4*)(Erow + lk00 + fr * 16 + lg * 4) = ev;
  }
  // ---- write half-1 tile (buf 1), barrier 2 ----
#pragma unroll
  for (int i = 0; i < 8; ++i) {
    int f = i * 512 + tid;
    int h4 = f & 1, lk = (f >> 1) & 127, q = f >> 8;
    int c = lk >> 5, slk = lk & 31;
#pragma unroll
    for (int e = 0; e < 4; ++e) {
      int hl = h4 * 4 + e;
      bt[1][c][hl][q][slk ^ (hl << 2)] = vv[i][e];
    }
  }
  __syncthreads();
  // ---- compute half 1 ----
#pragma unroll
  for (int fr = 0; fr < 8; ++fr) {
    int c = fr >> 1;
    const us* kr = Kh + (size_t)(lk00 + 128 + fr * 16 + la) * 64 + lg * 8;
    short8 kf0 = *(const short8*)kr;
    short8 kf1 = *(const short8*)(kr + 32);
    int lkb = ((fr & 1) * 16 + lg * 4) ^ (hh << 2);
    f32x4 a = *(const f32x4*)&bt[1][c][hh][la][lkb];
    a = MFMA16(kf0, qf[0], a);
    a = MFMA16(kf1, qf[1], a);
    u16x4 ev;
#pragma unroll
    for (int j = 0; j < 4; ++j) {
      float e = __expf(a[j]);
      lacc += e;
      ev[j] = f2b(e);
    }
    *(u16x4*)(Erow + lk00 + 128 + fr * 16 + lg * 4) = ev;
  }
  // ---- lsum: reduce across lg (lanes sharing q=la), per-kc partial ----
  {
    float s = lacc;
    s += __shfl_xor(s, 16);
    s += __shfl_xor(s, 32);
    if (lg == 0) lpart[kc * 32768 + (b * 16 + h) * 1024 + lq0 + la] = s;
  }
}

// ---------------- kernel 4: PV + transposed probs + gate ----------------
// Block (b,h,32q), 4 waves x 256 lk. linv merged in-block from lpart.
__global__ __launch_bounds__(256) void pv_k(
    const us* __restrict__ E, const us* __restrict__ Vt,
    const float* __restrict__ lpart, const float* __restrict__ G,
    float* __restrict__ outa, us* __restrict__ Ybf) {
  __shared__ char sm[49792];
  float* lv = (float*)(sm + 49664);
  int tid = threadIdx.x, lane = tid & 63, w = tid >> 6;
  int la = lane & 15, lg = lane >> 4;
  int bid = blockIdx.x;
  int g = bid >> 8, qt = (bid >> 3) & 31, xx = bid & 7;
  int bh = g * 8 + xx;
  int b = bh >> 4, h = bh & 15;
  int qb = qt * 32;
  if (tid < 32) {
    int r = bh * 1024 + qb + tid;
    float s = lpart[r] + lpart[32768 + r] + lpart[65536 + r] + lpart[98304 + r];
    lv[tid] = 1.f / s;
  }
  __syncthreads();
  char* pb = sm + w * 4096;  // [32 q][64 lk] bf16, chunk-XOR swizzle
  const us* Vh = Vt + (size_t)bh * 65536;
  f32x4 yacc[2][4] = {};
  int lkw = w * 256;

#pragma unroll 1
  for (int cc = 0; cc < 4; ++cc) {
    int lk0 = lkw + cc * 64;
    // stage E tile (reg-staged so dest can be swizzled)
#pragma unroll
    for (int it = 0; it < 4; ++it) {
      int ci = it * 64 + lane;
      int q = ci >> 3, c16 = ci & 7;
      short8 ev = *(const short8*)(E + (((size_t)(b * 1024 + qb + q) * 16 + h) << 10) + lk0 + c16 * 8);
      *(short8*)(pb + q * 128 + ((c16 * 16) ^ ((q & 7) << 4))) = ev;
    }
    // transposed probs: outa[b][lk][h][qb..qb+32)
#pragma unroll
    for (int it = 0; it < 8; ++it) {
      int idx = it * 64 + lane;
      int lkL = idx >> 3, q4 = idx & 7;
      f32x4 ov;
#pragma unroll
      for (int i = 0; i < 4; ++i) {
        int q = q4 * 4 + i;
        us e = *(const us*)(pb + q * 128 + ((2 * lkL) ^ ((q & 7) << 4)));
        ov[i] = b2f(e) * lv[q];
      }
      *(f32x4*)(outa + (((size_t)(b * 1024 + lk0 + lkL) * 16 + h) << 10) + qb + q4 * 4) = ov;
    }
    // PV
#pragma unroll
    for (int ks = 0; ks < 2; ++ks) {
      short8 pa[2];
#pragma unroll
      for (int qh = 0; qh < 2; ++qh) {
        int row = qh * 16 + la;
        pa[qh] = *(const short8*)(pb + row * 128 + ((ks * 64 + lg * 16) ^ ((row & 7) << 4)));
      }
#pragma unroll
      for (int ni = 0; ni < 4; ++ni) {
        short8 vf = *(const short8*)(Vh + (size_t)(ni * 16 + la) * 1024 + lk0 + ks * 32 + lg * 8);
        yacc[0][ni] = MFMA16(pa[0], vf, yacc[0][ni]);
        yacc[1][ni] = MFMA16(pa[1], vf, yacc[1][ni]);
      }
    }
  }

  // cross-wave O reduce + linv + gate
  float* red = (float*)(sm + 16384);  // [4 w][32 r][65]
#pragma unroll
  for (int qh = 0; qh < 2; ++qh)
#pragma unroll
    for (int ni = 0; ni < 4; ++ni)
#pragma unroll
      for (int j = 0; j < 4; ++j) {
        int r = qh * 16 + lg * 4 + j, c = ni * 16 + la;
        red[w * 2080 + r * 65 + c] = yacc[qh][ni][j];
      }
  __syncthreads();
#pragma unroll
  for (int rr = 0; rr < 8; ++rr) {
    int e = rr * 256 + tid;
    int r = e >> 6, c = e & 63;
    float s = red[r * 65 + c] + red[2080 + r * 65 + c] +
              red[4160 + r * 65 + c] + red[6240 + r * 65 + c];
    size_t gi = (((size_t)(b * 1024 + qb + r)) << 10) + h * 64 + c;
    Ybf[gi] = f2b(s * lv[r] * G[gi]);
  }
}

// ---------------- kernel 5: output projection ----------------
__global__ __launch_bounds__(256) void gemm_out_k(
    const us* __restrict__ Ybf, const us* __restrict__ Wobf,
    const float* __restrict__ bo, float* __restrict__ outy) {
  __shared__ char sm[32768];
  int bid = blockIdx.x;
  int swz = (bid & 7) * 16 + (bid >> 3);
  int tileM = swz >> 3, tileN = swz & 7;
  f32x4 acc[4][4] = {};
  gemm_main(Ybf, Wobf, tileM * 128, tileN * 128, acc, sm);
  int lane = threadIdx.x & 63, wid = threadIdx.x >> 6;
  int wr = wid >> 1, wc = wid & 1;
#pragma unroll
  for (int mi = 0; mi < 4; ++mi)
#pragma unroll
    for (int ni = 0; ni < 4; ++ni)
#pragma unroll
      for (int j = 0; j < 4; ++j) {
        int row = tileM * 128 + wr * 64 + mi * 16 + ((lane >> 4) << 2) + j;
        int col = tileN * 128 + wc * 64 + ni * 16 + (lane & 15);
        outy[(size_t)row * 1024 + col] = acc[mi][ni][j] + bo[col];
      }
}

extern "C" void kernel_launch(void* const* d_in, const int* in_sizes, int n_in,
                              void* d_out, int out_size, void* d_ws, size_t ws_size,
                              hipStream_t stream) {
  const float* x     = (const float*)d_in[0];
  const float* bias  = (const float*)d_in[1];
  const float* wproj = (const float*)d_in[2];
  const float* wo    = (const float*)d_in[3];
  const float* bo    = (const float*)d_in[4];
  const float* wg    = (const float*)d_in[5];
  const float* bg    = (const float*)d_in[6];
  float* outy = (float*)d_out;
  float* outa = outy + 2097152;  // y (2M f32), then probs (B,Lk,H,Lq) f32

  char* ws = (char*)d_ws;
  us*    Xbf  = (us*)(ws);
  us*    Wbf  = (us*)(ws + 4  * 1024 * 1024);
  us*    Wobf = (us*)(ws + 12 * 1024 * 1024);
  us*    Qb   = (us*)(ws + 14 * 1024 * 1024);
  us*    Kb   = (us*)(ws + 18 * 1024 * 1024);
  us*    Vt   = (us*)(ws + 22 * 1024 * 1024);
  float* G    = (float*)(ws + 26 * 1024 * 1024);
  us*    Ybf  = (us*)(ws + 34 * 1024 * 1024);
  float* lpart= (float*)(ws + (size_t)38 * 1024 * 1024);   // 512 KB
  us*    E    = (us*)   (ws + (size_t)40 * 1024 * 1024);   // 64 MB bf16
  if (ws_size < (size_t)104 * 1024 * 1024) return;

  prep_k<<<dim3(7168), dim3(256), 0, stream>>>(x, wproj, wg, wo, Xbf, Wbf, Wobf);
  gemm_qkvg_k<<<dim3(512), dim3(256), 0, stream>>>(Xbf, Wbf, Qb, Kb, Vt, G, bg);
  qke_k<<<dim3(1024), dim3(512), 0, stream>>>(Qb, Kb, bias, E, lpart);
  pv_k<<<dim3(1024), dim3(256), 0, stream>>>(E, Vt, lpart, G, outa, Ybf);
  gemm_out_k<<<dim3(128), dim3(256), 0, stream>>>(Ybf, Wobf, bo, outy);
}

// Round 20
// 195.137 us; speedup vs baseline: 1.1606x; 1.0247x over previous
//
#include <hip/hip_runtime.h>
#include <hip/hip_bf16.h>
#include <stdint.h>

typedef __attribute__((ext_vector_type(4))) float f32x4;
typedef __attribute__((ext_vector_type(8))) short short8;
typedef __attribute__((ext_vector_type(4))) unsigned short u16x4;
typedef unsigned short us;

#define DEV __device__ __forceinline__
#define MFMA16(a, b, c) __builtin_amdgcn_mfma_f32_16x16x32_bf16(a, b, c, 0, 0, 0)

DEV us f2b(float x) {
  union { float f; uint32_t u; } c; c.f = x;
  uint32_t r = (c.u + 0x7fffu + ((c.u >> 16) & 1u)) >> 16;
  return (us)r;
}
DEV float b2f(us x) {
  union { uint32_t u; float f; } c; c.u = ((uint32_t)x) << 16;
  return c.f;
}

DEV void gload_lds16(const void* g, void* l) {
  __builtin_amdgcn_global_load_lds((const __attribute__((address_space(1))) void*)g,
                                   (__attribute__((address_space(3))) void*)l, 16, 0, 0);
}

// ---------------- kernel 1: fp32 -> bf16 conversions ----------------
__global__ __launch_bounds__(256) void prep_k(
    const float* __restrict__ x, const float* __restrict__ wproj,
    const float* __restrict__ wg, const float* __restrict__ wo,
    us* __restrict__ Xbf, us* __restrict__ Wbf, us* __restrict__ Wobf) {
  int i = blockIdx.x * 256 + threadIdx.x;
  const float* src; us* dst;
  if (i < 524288)               { src = x     + (size_t)i * 4;                  dst = Xbf + (size_t)i * 4; }
  else if (i < 524288 + 786432) { int j = i - 524288;            src = wproj + (size_t)j * 4; dst = Wbf + (size_t)j * 4; }
  else if (i < 524288 + 786432 + 262144) { int j = i - (524288 + 786432); src = wg + (size_t)j * 4; dst = Wbf + 3145728 + (size_t)j * 4; }
  else                          { int j = i - (524288 + 786432 + 262144); src = wo + (size_t)j * 4; dst = Wobf + (size_t)j * 4; }
  f32x4 v = *(const f32x4*)src;
  u16x4 o; o.x = f2b(v.x); o.y = f2b(v.y); o.z = f2b(v.z); o.w = f2b(v.w);
  *(u16x4*)dst = o;
}

// ---------------- shared GEMM core (m97-style, 128x128) ----------------
DEV void gemm_stage(char* sm, const us* A, const us* Bw,
                    int tileMrow, int tileNrow, int buf, int kt, int lane, int wid) {
  const char* gA = (const char*)A;
  const char* gB = (const char*)Bw;
#pragma unroll
  for (int i = 0; i < 2; ++i) {
    int c = wid * 2 + i;
    int off = c * 1024 + lane * 16;
    int r = off >> 6, cb = off & 63;
    gload_lds16(gA + ((size_t)(tileMrow + r) * 2048) + kt * 64 + cb, sm + buf * 8192 + c * 1024);
    gload_lds16(gB + ((size_t)(tileNrow + r) * 2048) + kt * 64 + cb, sm + 16384 + buf * 8192 + c * 1024);
  }
}

DEV void gemm_main(const us* A, const us* Bw,
                   int tileMrow, int tileNrow, f32x4 acc[4][4], char* sm) {
  int tid = threadIdx.x, lane = tid & 63, wid = tid >> 6;
  int wr = wid >> 1, wc = wid & 1;
  gemm_stage(sm, A, Bw, tileMrow, tileNrow, 0, 0, lane, wid);
  for (int kt = 0; kt < 32; ++kt) {
    __syncthreads();
    if (kt < 31) gemm_stage(sm, A, Bw, tileMrow, tileNrow, (kt + 1) & 1, kt + 1, lane, wid);
    int ab = (kt & 1) * 8192;
    int rb = (lane & 15) * 64 + ((lane >> 4) * 16);
    short8 af[4], bf[4];
#pragma unroll
    for (int mi = 0; mi < 4; ++mi)
      af[mi] = *(const short8*)(sm + ab + (wr * 64 + mi * 16) * 64 + rb);
#pragma unroll
    for (int ni = 0; ni < 4; ++ni)
      bf[ni] = *(const short8*)(sm + 16384 + ab + (wc * 64 + ni * 16) * 64 + rb);
#pragma unroll
    for (int mi = 0; mi < 4; ++mi)
#pragma unroll
      for (int ni = 0; ni < 4; ++ni)
        acc[mi][ni] = MFMA16(af[mi], bf[ni], acc[mi][ni]);
  }
}

// ---------------- kernel 2: QKV+gate projection ----------------
__global__ __launch_bounds__(256) void gemm_qkvg_k(
    const us* __restrict__ Xbf, const us* __restrict__ Wbf,
    us* __restrict__ Qb, us* __restrict__ Kb, us* __restrict__ Vt,
    float* __restrict__ G, const float* __restrict__ bg) {
  __shared__ char sm[32768];
  int bid = blockIdx.x;
  int swz = (bid & 7) * 64 + (bid >> 3);
  int tileM = swz >> 5, tileN = swz & 31;
  f32x4 acc[4][4] = {};
  gemm_main(Xbf, Wbf, tileM * 128, tileN * 128, acc, sm);
  int lane = threadIdx.x & 63, wid = threadIdx.x >> 6;
  int wr = wid >> 1, wc = wid & 1;
#pragma unroll
  for (int mi = 0; mi < 4; ++mi)
#pragma unroll
    for (int ni = 0; ni < 4; ++ni)
#pragma unroll
      for (int j = 0; j < 4; ++j) {
        int row = tileM * 128 + wr * 64 + mi * 16 + ((lane >> 4) << 2) + j;
        int col = tileN * 128 + wc * 64 + ni * 16 + (lane & 15);
        float v = acc[mi][ni][j];
        int b = row >> 10, l = row & 1023;
        if (col < 3072) {
          int h = col / 192, r = col - h * 192;
          size_t base = ((size_t)(b * 16 + h) * 1024 + l) * 64;
          if (r < 64)        Qb[base + r] = f2b(v * 0.125f);
          else if (r < 128)  Kb[base + (r - 64)] = f2b(v);
          else               Vt[((size_t)(b * 16 + h) * 64 + (r - 128)) * 1024 + l] = f2b(v);
        } else {
          int e = col - 3072;
          float s = v + bg[e];
          G[(size_t)row * 1024 + e] = 1.f / (1.f + __expf(-s));
        }
      }
}

// ---------------- kernel 3: fused QK^T + bias + exp -> E, lsum partials ----------------
// R11-best: block (b, qt:16q, kc:256lk, hg:8 heads); 8 waves, one head/wave.
// Bias staged in 128-lk halves (8-deep load queue), double-buffered, TWO
// barriers per block; half-1 loads issued before half-0 compute.
__global__ __launch_bounds__(512, 4) void qke_k(
    const us* __restrict__ Qb, const us* __restrict__ Kb,
    const float* __restrict__ bias, us* __restrict__ E,
    float* __restrict__ lpart) {
  __shared__ float bt[2][4][8][16][36];   // [buf][chunk32][hl][q][slk^ pad36]
  int tid = threadIdx.x, lane = tid & 63, w = tid >> 6;
  int la = lane & 15, lg = lane >> 4;
  int bid = blockIdx.x;
  int b = (bid & 7) >> 2, kc = bid & 3;
  int hg = (bid >> 3) & 1, qt = bid >> 4;
  int lq0 = qt * 16, lk00 = kc * 256;
  int h = hg * 8 + w, hh = w;

  short8 qf[2];
  {
    size_t bh = (size_t)(b * 16 + h);
#pragma unroll
    for (int ks = 0; ks < 2; ++ks)
      qf[ks] = *(const short8*)(Qb + bh * 65536 + (size_t)(lq0 + la) * 64 + ks * 32 + lg * 8);
  }
  const us* Kh = Kb + (size_t)(b * 16 + h) * 65536;
  const float* bsrc = bias + ((size_t)b << 24) + ((size_t)lq0 << 14) + hg * 8;
  us* Erow = E + (((size_t)(b * 1024 + lq0 + la) * 16 + h) << 10);

  f32x4 vv[8];
  // ---- stage half 0: 8 loads issued back-to-back, then writes ----
#pragma unroll
  for (int i = 0; i < 8; ++i) {
    int f = i * 512 + tid;
    int h4 = f & 1, lk = (f >> 1) & 127, q = f >> 8;
    vv[i] = *(const f32x4*)(bsrc + ((size_t)q << 14) + ((size_t)(lk00 + lk) << 4) + h4 * 4);
  }
#pragma unroll
  for (int i = 0; i < 8; ++i) {
    int f = i * 512 + tid;
    int h4 = f & 1, lk = (f >> 1) & 127, q = f >> 8;
    int c = lk >> 5, slk = lk & 31;
#pragma unroll
    for (int e = 0; e < 4; ++e) {
      int hl = h4 * 4 + e;
      bt[0][c][hl][q][slk ^ (hl << 2)] = vv[i][e];
    }
  }
  __syncthreads();   // barrier 1: half-0 tile ready

  float lacc = 0.f;
  // ---- issue half-1 loads (latency hides under half-0 compute) ----
#pragma unroll
  for (int i = 0; i < 8; ++i) {
    int f = i * 512 + tid;
    int h4 = f & 1, lk = (f >> 1) & 127, q = f >> 8;
    vv[i] = *(const f32x4*)(bsrc + ((size_t)q << 14) + ((size_t)(lk00 + 128 + lk) << 4) + h4 * 4);
  }
  // ---- compute half 0: 8 fr, no barriers ----
#pragma unroll
  for (int fr = 0; fr < 8; ++fr) {
    int c = fr >> 1;
    const us* kr = Kh + (size_t)(lk00 + fr * 16 + la) * 64 + lg * 8;
    short8 kf0 = *(const short8*)kr;
    short8 kf1 = *(const short8*)(kr + 32);
    int lkb = ((fr & 1) * 16 + lg * 4) ^ (hh << 2);
    f32x4 a = *(const f32x4*)&bt[0][c][hh][la][lkb];
    a = MFMA16(kf0, qf[0], a);
    a = MFMA16(kf1, qf[1], a);
    u16x4 ev;
#pragma unroll
    for (int j = 0; j < 4; ++j) {
      float e = __expf(a[j]);
      lacc += e;
      ev[j] = f2b(e);
    }
    *(u16x4*)(Erow + lk00 + fr * 16 + lg * 4) = ev;
  }
  // ---- write half-1 tile (buf 1), barrier 2 ----
#pragma unroll
  for (int i = 0; i < 8; ++i) {
    int f = i * 512 + tid;
    int h4 = f & 1, lk = (f >> 1) & 127, q = f >> 8;
    int c = lk >> 5, slk = lk & 31;
#pragma unroll
    for (int e = 0; e < 4; ++e) {
      int hl = h4 * 4 + e;
      bt[1][c][hl][q][slk ^ (hl << 2)] = vv[i][e];
    }
  }
  __syncthreads();
  // ---- compute half 1 ----
#pragma unroll
  for (int fr = 0; fr < 8; ++fr) {
    int c = fr >> 1;
    const us* kr = Kh + (size_t)(lk00 + 128 + fr * 16 + la) * 64 + lg * 8;
    short8 kf0 = *(const short8*)kr;
    short8 kf1 = *(const short8*)(kr + 32);
    int lkb = ((fr & 1) * 16 + lg * 4) ^ (hh << 2);
    f32x4 a = *(const f32x4*)&bt[1][c][hh][la][lkb];
    a = MFMA16(kf0, qf[0], a);
    a = MFMA16(kf1, qf[1], a);
    u16x4 ev;
#pragma unroll
    for (int j = 0; j < 4; ++j) {
      float e = __expf(a[j]);
      lacc += e;
      ev[j] = f2b(e);
    }
    *(u16x4*)(Erow + lk00 + 128 + fr * 16 + lg * 4) = ev;
  }
  // ---- lsum: reduce across lg (lanes sharing q=la), per-kc partial ----
  {
    float s = lacc;
    s += __shfl_xor(s, 16);
    s += __shfl_xor(s, 32);
    if (lg == 0) lpart[kc * 32768 + (b * 16 + h) * 1024 + lq0 + la] = s;
  }
}

// ---------------- kernel 4: PV + transposed probs + gate ----------------
// Block (b,h,32q), 4 waves x 256 lk. linv merged in-block from lpart.
__global__ __launch_bounds__(256) void pv_k(
    const us* __restrict__ E, const us* __restrict__ Vt,
    const float* __restrict__ lpart, const float* __restrict__ G,
    float* __restrict__ outa, us* __restrict__ Ybf) {
  __shared__ char sm[49792];
  float* lv = (float*)(sm + 49664);
  int tid = threadIdx.x, lane = tid & 63, w = tid >> 6;
  int la = lane & 15, lg = lane >> 4;
  int bid = blockIdx.x;
  int g = bid >> 8, qt = (bid >> 3) & 31, xx = bid & 7;
  int bh = g * 8 + xx;
  int b = bh >> 4, h = bh & 15;
  int qb = qt * 32;
  if (tid < 32) {
    int r = bh * 1024 + qb + tid;
    float s = lpart[r] + lpart[32768 + r] + lpart[65536 + r] + lpart[98304 + r];
    lv[tid] = 1.f / s;
  }
  __syncthreads();
  char* pb = sm + w * 4096;  // [32 q][64 lk] bf16, chunk-XOR swizzle
  const us* Vh = Vt + (size_t)bh * 65536;
  f32x4 yacc[2][4] = {};
  int lkw = w * 256;

#pragma unroll 1
  for (int cc = 0; cc < 4; ++cc) {
    int lk0 = lkw + cc * 64;
    // stage E tile (reg-staged so dest can be swizzled)
#pragma unroll
    for (int it = 0; it < 4; ++it) {
      int ci = it * 64 + lane;
      int q = ci >> 3, c16 = ci & 7;
      short8 ev = *(const short8*)(E + (((size_t)(b * 1024 + qb + q) * 16 + h) << 10) + lk0 + c16 * 8);
      *(short8*)(pb + q * 128 + ((c16 * 16) ^ ((q & 7) << 4))) = ev;
    }
    // transposed probs: outa[b][lk][h][qb..qb+32)
#pragma unroll
    for (int it = 0; it < 8; ++it) {
      int idx = it * 64 + lane;
      int lkL = idx >> 3, q4 = idx & 7;
      f32x4 ov;
#pragma unroll
      for (int i = 0; i < 4; ++i) {
        int q = q4 * 4 + i;
        us e = *(const us*)(pb + q * 128 + ((2 * lkL) ^ ((q & 7) << 4)));
        ov[i] = b2f(e) * lv[q];
      }
      *(f32x4*)(outa + (((size_t)(b * 1024 + lk0 + lkL) * 16 + h) << 10) + qb + q4 * 4) = ov;
    }
    // PV
#pragma unroll
    for (int ks = 0; ks < 2; ++ks) {
      short8 pa[2];
#pragma unroll
      for (int qh = 0; qh < 2; ++qh) {
        int row = qh * 16 + la;
        pa[qh] = *(const short8*)(pb + row * 128 + ((ks * 64 + lg * 16) ^ ((row & 7) << 4)));
      }
#pragma unroll
      for (int ni = 0; ni < 4; ++ni) {
        short8 vf = *(const short8*)(Vh + (size_t)(ni * 16 + la) * 1024 + lk0 + ks * 32 + lg * 8);
        yacc[0][ni] = MFMA16(pa[0], vf, yacc[0][ni]);
        yacc[1][ni] = MFMA16(pa[1], vf, yacc[1][ni]);
      }
    }
  }

  // cross-wave O reduce + linv + gate
  float* red = (float*)(sm + 16384);  // [4 w][32 r][65]
#pragma unroll
  for (int qh = 0; qh < 2; ++qh)
#pragma unroll
    for (int ni = 0; ni < 4; ++ni)
#pragma unroll
      for (int j = 0; j < 4; ++j) {
        int r = qh * 16 + lg * 4 + j, c = ni * 16 + la;
        red[w * 2080 + r * 65 + c] = yacc[qh][ni][j];
      }
  __syncthreads();
#pragma unroll
  for (int rr = 0; rr < 8; ++rr) {
    int e = rr * 256 + tid;
    int r = e >> 6, c = e & 63;
    float s = red[r * 65 + c] + red[2080 + r * 65 + c] +
              red[4160 + r * 65 + c] + red[6240 + r * 65 + c];
    size_t gi = (((size_t)(b * 1024 + qb + r)) << 10) + h * 64 + c;
    Ybf[gi] = f2b(s * lv[r] * G[gi]);
  }
}

// ---------------- kernel 5: output projection ----------------
__global__ __launch_bounds__(256) void gemm_out_k(
    const us* __restrict__ Ybf, const us* __restrict__ Wobf,
    const float* __restrict__ bo, float* __restrict__ outy) {
  __shared__ char sm[32768];
  int bid = blockIdx.x;
  int swz = (bid & 7) * 16 + (bid >> 3);
  int tileM = swz >> 3, tileN = swz & 7;
  f32x4 acc[4][4] = {};
  gemm_main(Ybf, Wobf, tileM * 128, tileN * 128, acc, sm);
  int lane = threadIdx.x & 63, wid = threadIdx.x >> 6;
  int wr = wid >> 1, wc = wid & 1;
#pragma unroll
  for (int mi = 0; mi < 4; ++mi)
#pragma unroll
    for (int ni = 0; ni < 4; ++ni)
#pragma unroll
      for (int j = 0; j < 4; ++j) {
        int row = tileM * 128 + wr * 64 + mi * 16 + ((lane >> 4) << 2) + j;
        int col = tileN * 128 + wc * 64 + ni * 16 + (lane & 15);
        outy[(size_t)row * 1024 + col] = acc[mi][ni][j] + bo[col];
      }
}

extern "C" void kernel_launch(void* const* d_in, const int* in_sizes, int n_in,
                              void* d_out, int out_size, void* d_ws, size_t ws_size,
                              hipStream_t stream) {
  const float* x     = (const float*)d_in[0];
  const float* bias  = (const float*)d_in[1];
  const float* wproj = (const float*)d_in[2];
  const float* wo    = (const float*)d_in[3];
  const float* bo    = (const float*)d_in[4];
  const float* wg    = (const float*)d_in[5];
  const float* bg    = (const float*)d_in[6];
  float* outy = (float*)d_out;
  float* outa = outy + 2097152;  // y (2M f32), then probs (B,Lk,H,Lq) f32

  char* ws = (char*)d_ws;
  us*    Xbf  = (us*)(ws);
  us*    Wbf  = (us*)(ws + 4  * 1024 * 1024);
  us*    Wobf = (us*)(ws + 12 * 1024 * 1024);
  us*    Qb   = (us*)(ws + 14 * 1024 * 1024);
  us*    Kb   = (us*)(ws + 18 * 1024 * 1024);
  us*    Vt   = (us*)(ws + 22 * 1024 * 1024);
  float* G    = (float*)(ws + 26 * 1024 * 1024);
  us*    Ybf  = (us*)(ws + 34 * 1024 * 1024);
  float* lpart= (float*)(ws + (size_t)38 * 1024 * 1024);   // 512 KB
  us*    E    = (us*)   (ws + (size_t)40 * 1024 * 1024);   // 64 MB bf16
  if (ws_size < (size_t)104 * 1024 * 1024) return;

  prep_k<<<dim3(7168), dim3(256), 0, stream>>>(x, wproj, wg, wo, Xbf, Wbf, Wobf);
  gemm_qkvg_k<<<dim3(512), dim3(256), 0, stream>>>(Xbf, Wbf, Qb, Kb, Vt, G, bg);
  qke_k<<<dim3(1024), dim3(512), 0, stream>>>(Qb, Kb, bias, E, lpart);
  pv_k<<<dim3(1024), dim3(256), 0, stream>>>(E, Vt, lpart, G, outa, Ybf);
  gemm_out_k<<<dim3(128), dim3(256), 0, stream>>>(Ybf, Wobf, bo, outy);
}